// Round 3
// baseline (177.285 us; speedup 1.0000x reference)
//
#include <hip/hip_runtime.h>
#include <hip/hip_bf16.h>

typedef __attribute__((ext_vector_type(8))) short short8;
typedef __attribute__((ext_vector_type(4))) float floatx4;

// Problem constants: T=1024, B=4, E=1024, H=16, D=64, L=16
// Inputs/outputs fp32; internals bf16 MFMA with fp32 accumulation.
// Softmax runs in the exp2 domain: q is pre-scaled by 0.125*log2(e), so
// scores (qk + rel-bias) are already in log2 units and p = exp2(s).

#define QSCALE 0.18033688011112043f   // 0.125 * log2(e)

__device__ __forceinline__ short f2bf(float x) {
  union { float f; unsigned u; } cv; cv.f = x;
  unsigned u = cv.u + (0x7FFFu + ((cv.u >> 16) & 1u));  // RNE
  return (short)(u >> 16);
}

// gfx950 v_cvt_pk_bf16_f32 via hip_bf16 API: 1 VALU op per 2 values.
__device__ __forceinline__ unsigned pk_bf16(float a, float b) {
  union { __hip_bfloat162 h; unsigned u; } cv;
  cv.h = __float22bfloat162_rn(make_float2(a, b));
  return cv.u;
}

// v_exp_f32 computes 2^x directly.
__device__ __forceinline__ float exp2_hw(float x) {
  return __builtin_amdgcn_exp2f(x);
}

__device__ __forceinline__ floatx4 mfma16(short8 a, short8 b, floatx4 c) {
  return __builtin_amdgcn_mfma_f32_16x16x32_bf16(a, b, c, 0, 0, 0);
}

__device__ __forceinline__ void async_copy16(const void* g, void* l) {
  __builtin_amdgcn_global_load_lds((const __attribute__((address_space(1))) void*)g,
                                   (__attribute__((address_space(3))) void*)l, 16, 0, 0);
}

// ---------------------------------------------------------------------------
// Kernel 0: fp32 -> bf16 for query / in_proj_weight / out_w in ONE launch.
// query is ALSO transposed (T,B,E) -> (B,T,E).
// ---------------------------------------------------------------------------
__global__ void __launch_bounds__(256) convert_all_kernel(
    const float* __restrict__ s0, const float* __restrict__ s1,
    const float* __restrict__ s2,
    short* __restrict__ d0, short* __restrict__ d1, short* __restrict__ d2)
{
  int i = blockIdx.x * 256 + threadIdx.x;
  if (i < 524288) {               // query with transpose
    int e8 = i & 127, b = (i >> 7) & 3, t = i >> 9;
    const float4* s = (const float4*)s0 + (size_t)i * 2;
    float4 a = s[0], c = s[1];
    uint4 o = make_uint4(pk_bf16(a.x, a.y), pk_bf16(a.z, a.w),
                         pk_bf16(c.x, c.y), pk_bf16(c.z, c.w));
    *(uint4*)(d0 + (size_t)b * 1048576 + t * 1024 + e8 * 8) = o;
  } else {                        // weights, straight copy
    const float* src; short* dst; int off;
    if (i < 917504) { src = s1; dst = d1; off = i - 524288; }
    else            { src = s2; dst = d2; off = i - 917504; }
    const float4* s = (const float4*)src + (size_t)off * 2;
    float4 a = s[0], c = s[1];
    uint4 o = make_uint4(pk_bf16(a.x, a.y), pk_bf16(a.z, a.w),
                         pk_bf16(c.x, c.y), pk_bf16(c.z, c.w));
    *(uint4*)(dst + (size_t)off * 8) = o;
  }
}

// ---------------------------------------------------------------------------
// Kernel 1: qkv = query_bt @ in_proj_weight^T + bias. 8-phase 256x256 tile,
// BK=64, 8 waves (2Mx4N), counted-vmcnt pipeline (T3+T4), setprio (T5),
// xor-8 swizzled LDS (conflict-free ds_read_b128, 2-way max).
// grid 192 (1D, XCD-affinity decode), block 512.
//
// XCD affinity: block (bx,by) writes q/k/v rows for bh-group
//   G = 2*(bx>>2) + ((by&3)>>1)   (b = bx>>2; heads 4*(by&3)..+3)
// attn_kernel consumes bh-group G on XCD G (its blk&7 == bh>>3). Writes
// allocate in the producer's XCD L2, so we place this block on XCD G too:
// linear id lin = G + 8*idx (round-robin dispatch -> XCD = lin&7).
// Decode: g=lin&7, idx=lin>>3, bx=(g>>1)*4+(idx&3),
//         by=((idx>>2)>>1)*4 + (g&1)*2 + ((idx>>2)&1).  Bijective.
//
// ONE barrier per phase (m201 template): {reads | DMA issue | (vmcnt @P3) |
// s_barrier | setprio(1) 16xMFMA setprio(0)}. WAR: DMA issued in phase p
// targets a region whose last ds_read was in phase <= p-1; barrier(p-1)
// publishes those reads. RAW: vmcnt(4) @P3 retires A(kt+1)+B(kt+1).
// Tail: clamped source index, unclamped buffer parity (ghost loads land in
// dead regions, uniform vmcnt bookkeeping).
// ---------------------------------------------------------------------------
__device__ __forceinline__ void stage_half8(const short* __restrict__ g,
                                            short* l, int tid, int w) {
  #pragma unroll
  for (int i = 0; i < 2; i++) {
    int seg = i * 512 + tid;            // 1024 segs of 16B = 128x64 bf16 half
    int row = seg >> 3, p = seg & 7;
    int ck = p ^ (row & 7);             // global chunk landing at slot p
    async_copy16(g + (size_t)row * 1024 + ck * 8,
                 l + (size_t)(i * 512 + w * 64) * 8);
  }
}

__global__ void __launch_bounds__(512, 2) gemm_qkv(
    const short* __restrict__ A, const short* __restrict__ W,
    const float* __restrict__ bias,
    short* __restrict__ q_ws, short* __restrict__ k_ws, short* __restrict__ v_ws)
{
  __shared__ __align__(16) short Atile[2 * 2 * 128 * 64];   // 64 KB
  __shared__ __align__(16) short Btile[2 * 2 * 128 * 64];   // 64 KB
  const int tid = threadIdx.x, lane = tid & 63, w = tid >> 6;
  const int quad = lane >> 4, l16 = lane & 15;
  // XCD-affinity decode (see header comment)
  const int lin = (int)blockIdx.x;          // 0..191
  const int g = lin & 7, idx = lin >> 3;    // g = consumer XCD (bh>>3)
  const int bxl = idx & 3, iby = idx >> 2;  // bxl 0..3, iby 0..5
  const int bx = (g >> 1) * 4 + bxl;                          // 0..15
  const int by = (iby >> 1) * 4 + (g & 1) * 2 + (iby & 1);    // 0..11
  const int m0 = bx * 256, n0 = by * 256;
  const int wm = (w >> 2) * 128, wn = (w & 3) * 64;
  const int rowB0 = (w & 1) * 64;       // wave's 64-row window inside B half

  const short* Ag = A + (size_t)m0 * 1024;
  const short* Wg = W + (size_t)n0 * 1024;

  floatx4 acc[8][4];
  #pragma unroll
  for (int mt = 0; mt < 8; mt++)
    #pragma unroll
    for (int nt = 0; nt < 4; nt++) acc[mt][nt] = (floatx4)(0.0f);

  #define SH_A(kc, h, buf) stage_half8(Ag + (size_t)(h) * 131072 + (kc) * 64, \
                                       Atile + (buf) * 16384 + (h) * 8192, tid, w)
  #define SH_B(kc, h, buf) stage_half8(Wg + (size_t)(h) * 131072 + (kc) * 64, \
                                       Btile + (buf) * 16384 + (h) * 8192, tid, w)

  // prologue: tile0 fully + A halves of tile1 (B halves of tile1 come @kt=0)
  SH_A(0, 0, 0); SH_A(0, 1, 0); SH_B(0, 0, 0); SH_B(0, 1, 0);
  SH_A(1, 0, 1); SH_A(1, 1, 1);
  asm volatile("s_waitcnt vmcnt(4)" ::: "memory");   // tile0 landed
  __builtin_amdgcn_s_barrier();

  for (int kt = 0; kt < 16; ++kt) {
    const int cur = kt & 1, nxt = cur ^ 1;
    const short* Ah = Atile + cur * 16384 + (w >> 2) * 8192;
    const short* Bh = Btile + cur * 16384 + ((w & 3) >> 1) * 8192;
    const int kc1 = (kt + 1 < 16) ? kt + 1 : 15;   // B source (buf nxt)
    const int kc2 = (kt + 2 < 16) ? kt + 2 : 15;   // A source (buf cur)

    short8 alo[4][2], ahi[4][2], blo[2][2], bhi[2][2];

    // ---------------- P0: A-lo + B-lo reads; DMA B0(kt+1) ----------------
    #pragma unroll
    for (int mt = 0; mt < 4; mt++) {
      int r = mt * 16 + l16;
      #pragma unroll
      for (int ks = 0; ks < 2; ks++)
        alo[mt][ks] = *(const short8*)(Ah + r * 64 + (((quad + 4 * ks) ^ (r & 7)) << 3));
    }
    #pragma unroll
    for (int nt = 0; nt < 2; nt++) {
      int r = rowB0 + nt * 16 + l16;
      #pragma unroll
      for (int ks = 0; ks < 2; ks++)
        blo[nt][ks] = *(const short8*)(Bh + r * 64 + (((quad + 4 * ks) ^ (r & 7)) << 3));
    }
    SH_B(kc1, 0, nxt);
    __builtin_amdgcn_s_barrier();
    __builtin_amdgcn_s_setprio(1);
    #pragma unroll
    for (int mt = 0; mt < 4; mt++)
      #pragma unroll
      for (int nt = 0; nt < 2; nt++)
        #pragma unroll
        for (int ks = 0; ks < 2; ks++)
          acc[mt][nt] = mfma16(alo[mt][ks], blo[nt][ks], acc[mt][nt]);
    __builtin_amdgcn_s_setprio(0);

    // ---------------- P1: A-hi reads; DMA B1(kt+1) ----------------
    #pragma unroll
    for (int mt = 0; mt < 4; mt++) {
      int r = 64 + mt * 16 + l16;
      #pragma unroll
      for (int ks = 0; ks < 2; ks++)
        ahi[mt][ks] = *(const short8*)(Ah + r * 64 + (((quad + 4 * ks) ^ (r & 7)) << 3));
    }
    SH_B(kc1, 1, nxt);
    __builtin_amdgcn_s_barrier();
    __builtin_amdgcn_s_setprio(1);
    #pragma unroll
    for (int mt = 0; mt < 4; mt++)
      #pragma unroll
      for (int nt = 0; nt < 2; nt++)
        #pragma unroll
        for (int ks = 0; ks < 2; ks++)
          acc[4 + mt][nt] = mfma16(ahi[mt][ks], blo[nt][ks], acc[4 + mt][nt]);
    __builtin_amdgcn_s_setprio(0);

    // ---------------- P2: B-hi reads; DMA A0(kt+2) ----------------
    #pragma unroll
    for (int nt = 0; nt < 2; nt++) {
      int r = rowB0 + (2 + nt) * 16 + l16;
      #pragma unroll
      for (int ks = 0; ks < 2; ks++)
        bhi[nt][ks] = *(const short8*)(Bh + r * 64 + (((quad + 4 * ks) ^ (r & 7)) << 3));
    }
    SH_A(kc2, 0, cur);
    __builtin_amdgcn_s_barrier();
    __builtin_amdgcn_s_setprio(1);
    #pragma unroll
    for (int mt = 0; mt < 4; mt++)
      #pragma unroll
      for (int nt = 0; nt < 2; nt++)
        #pragma unroll
        for (int ks = 0; ks < 2; ks++)
          acc[4 + mt][2 + nt] = mfma16(ahi[mt][ks], bhi[nt][ks], acc[4 + mt][2 + nt]);
    __builtin_amdgcn_s_setprio(0);

    // ---------------- P3: DMA A1(kt+2); counted wait; pure-reg MFMA ------
    SH_A(kc2, 1, cur);
    asm volatile("s_waitcnt vmcnt(4)" ::: "memory");   // tile kt+1 landed
    __builtin_amdgcn_s_barrier();
    __builtin_amdgcn_s_setprio(1);
    #pragma unroll
    for (int mt = 0; mt < 4; mt++)
      #pragma unroll
      for (int nt = 0; nt < 2; nt++)
        #pragma unroll
        for (int ks = 0; ks < 2; ks++)
          acc[mt][2 + nt] = mfma16(alo[mt][ks], bhi[nt][ks], acc[mt][2 + nt]);
    __builtin_amdgcn_s_setprio(0);
  }
  #undef SH_A
  #undef SH_B

  // drain ghost DMAs before LDS deallocation / kernel end
  asm volatile("s_waitcnt vmcnt(0)" ::: "memory");

  const int which = n0 >> 10;                 // 0=q 1=k 2=v (block-uniform)
  #pragma unroll
  for (int nt = 0; nt < 4; nt++) {
    int f = n0 + wn + nt * 16 + l16;          // 0..3071
    float bv = bias[f];
    int h = (f >> 6) & 15;
    int d = f & 63;
    if (which == 2) {
      #pragma unroll
      for (int mt = 0; mt < 8; mt++) {
        int r0 = m0 + wm + mt * 16 + quad * 4;    // row = b*1024 + t
        int t = r0 & 1023, bb = r0 >> 10;
        int bh = bb * 16 + h;
        unsigned lo = pk_bf16(acc[mt][nt][0] + bv, acc[mt][nt][1] + bv);
        unsigned hi = pk_bf16(acc[mt][nt][2] + bv, acc[mt][nt][3] + bv);
        *(uint2*)(v_ws + ((size_t)bh * 64 + d) * 1024 + t) = make_uint2(lo, hi);
      }
    } else {
      short* dst = which ? k_ws : q_ws;
      const float sc = which ? 1.0f : QSCALE;
      #pragma unroll
      for (int mt = 0; mt < 8; mt++) {
        int r0 = m0 + wm + mt * 16 + quad * 4;
        int t = r0 & 1023, bb = r0 >> 10;
        int bh = bb * 16 + h;
        unsigned u01 = pk_bf16((acc[mt][nt][0] + bv) * sc, (acc[mt][nt][1] + bv) * sc);
        unsigned u23 = pk_bf16((acc[mt][nt][2] + bv) * sc, (acc[mt][nt][3] + bv) * sc);
        size_t base = ((size_t)bh * 1024 + t) * 64 + d;
        dst[base]           = (short)u01;
        dst[base + 64]      = (short)(u01 >> 16);
        dst[base + 128]     = (short)u23;
        dst[base + 192]     = (short)(u23 >> 16);
      }
    }
  }
}

// ---------------------------------------------------------------------------
// Kernel 2: flash-style attention, S^T formulation, 2 q-groups per wave.
//  - K/V double-buffered: ONE barrier per s-tile, DMA(t+1) flies under
//    compute(t). LDS 66 KB is free: occupancy is grid-capped at 2 blocks/CU.
//  - XCD head-affinity swizzle keeps per-head K/V L2-resident (FETCH 12 MB).
//  - exp2-domain softmax: p = 2^s via v_exp_f32, q pre-scaled by QSCALE.
//  - T5 setprio around QK and PV MFMA clusters (2 independent blocks/CU
//    give the scheduler role diversity to arbitrate).
// block = (bh, 128 q-rows); 4 waves. grid 512, block 256.
// ---------------------------------------------------------------------------
__global__ void __launch_bounds__(256) attn_kernel(
    const short* __restrict__ q_ws, const short* __restrict__ k_ws,
    const short* __restrict__ v_ws, const float* __restrict__ relk,
    short* __restrict__ attn_ws)
{
  __shared__ float rel_lds[128 * 33];                   // 16896 B
  __shared__ __align__(16) short Ktile[2][64 * 64];     // 16384 B
  __shared__ __align__(16) short Vtile[2][64 * 64];     // 16384 B
  __shared__ __align__(16) short p_lds[4][32 * 64];     // 16384 B
  const int tid = threadIdx.x, lane = tid & 63, w = tid >> 6;
  const int quad = lane >> 4, l16 = lane & 15;
  // XCD swizzle: head = 8*(blk&7) + (blk>>3)&7, chunk = blk>>6
  const int bh = 8 * ((int)blockIdx.x & 7) + (((int)blockIdx.x >> 3) & 7);
  const int t0 = ((int)blockIdx.x >> 6) * 128;
  const int b = bh >> 4, h = bh & 15;

  // Q fragments: q-row(qt) = t0 + qt*64 + w*16 + l16
  short8 aq[2][2];
  #pragma unroll
  for (int qt = 0; qt < 2; qt++)
    #pragma unroll
    for (int ks = 0; ks < 2; ks++)
      aq[qt][ks] = *(const short8*)(q_ws
          + ((size_t)bh * 1024 + t0 + qt * 64 + w * 16 + l16) * 64
          + ks * 32 + quad * 8);

  // ---- stage relk[0:33][0:64] as bf16 into Ktile[0] (xor-swizzled, pad 48)
  for (int i = tid; i < 48 * 8; i += 256) {
    int row = i >> 3, p = i & 7;
    short8 val;
    if (row < 33) {
      const float* src = relk + row * 1024 + p * 8;
      float4 a = *(const float4*)src, c = *(const float4*)(src + 4);
      val[0] = f2bf(a.x); val[1] = f2bf(a.y); val[2] = f2bf(a.z); val[3] = f2bf(a.w);
      val[4] = f2bf(c.x); val[5] = f2bf(c.y); val[6] = f2bf(c.z); val[7] = f2bf(c.w);
    } else {
      val = (short8)0;
    }
    *(short8*)(Ktile[0] + row * 64 + ((p ^ (row & 7)) << 3)) = val;
  }
  __syncthreads();

  // ---- rel_lds[tl][j] = q[tl] . relk[j]   (log2-domain, q pre-scaled)
  #pragma unroll
  for (int qt = 0; qt < 2; qt++) {
    #pragma unroll
    for (int jt = 0; jt < 3; jt++) {
      floatx4 scR = (floatx4)(0.0f);
      #pragma unroll
      for (int ks = 0; ks < 2; ks++) {
        int rrow = jt * 16 + l16;
        int ck = (quad + 4 * ks) ^ (rrow & 7);
        short8 rb = *(const short8*)(Ktile[0] + rrow * 64 + ck * 8);
        scR = mfma16(aq[qt][ks], rb, scR);
      }
      int j = jt * 16 + l16;
      if (j < 33) {
        #pragma unroll
        for (int reg = 0; reg < 4; reg++) {
          int tl = qt * 64 + w * 16 + quad * 4 + reg;
          rel_lds[tl * 33 + j] = scR[reg];
        }
      }
    }
  }
  __syncthreads();   // rel_lds ready; Ktile free for K/V staging

  float biasLo[2], biasHi[2];
  #pragma unroll
  for (int qt = 0; qt < 2; qt++) {
    int ql = qt * 64 + w * 16 + l16;
    biasLo[qt] = rel_lds[ql * 33 + 0];
    biasHi[qt] = rel_lds[ql * 33 + 32];
  }

  floatx4 o[2][4];
  #pragma unroll
  for (int qt = 0; qt < 2; qt++)
    #pragma unroll
    for (int dt = 0; dt < 4; dt++) o[qt][dt] = (floatx4)(0.0f);
  float rsum[2] = {0.f, 0.f};

  const short* kg = k_ws + (size_t)bh * 1024 * 64;
  const short* vg = v_ws + (size_t)bh * 64 * 1024;

  #define STAGE_KV(S0, BUF)                                                  \
    {                                                                        \
      _Pragma("unroll")                                                      \
      for (int i = 0; i < 2; i++) {                                          \
        int seg = i * 256 + tid;                                             \
        int row = seg >> 3, p = seg & 7;                                     \
        int ck = p ^ (row & 7);                                              \
        async_copy16(kg + (size_t)((S0) + row) * 64 + ck * 8,                \
                     Ktile[BUF] + (size_t)(i * 256 + w * 64) * 8);           \
        async_copy16(vg + (size_t)row * 1024 + (S0) + ck * 8,                \
                     Vtile[BUF] + (size_t)(i * 256 + w * 64) * 8);           \
      }                                                                      \
    }

  STAGE_KV(0, 0);

  for (int st = 0; st < 16; st++) {
    const int s0 = st * 64;
    const int cur = st & 1;
    __syncthreads();                // drains DMA(st); WAR for DMA(st+1)
    if (st < 15) STAGE_KV(s0 + 64, 1 - cur);

    // ---- K fragments once into registers, reused by both q-groups ----
    short8 kb[4][2];
    #pragma unroll
    for (int nt = 0; nt < 4; nt++)
      #pragma unroll
      for (int ks = 0; ks < 2; ks++) {
        int srow = nt * 16 + l16;
        kb[nt][ks] = *(const short8*)(Ktile[cur] + srow * 64
                                      + (((quad + 4 * ks) ^ (l16 & 7)) << 3));
      }

    // ---- S^T = K Q^T for both q-groups ----
    floatx4 sc[2][4];
    __builtin_amdgcn_s_setprio(1);
    #pragma unroll
    for (int qt = 0; qt < 2; qt++)
      #pragma unroll
      for (int nt = 0; nt < 4; nt++) {
        sc[qt][nt] = (floatx4)(0.0f);
        #pragma unroll
        for (int ks = 0; ks < 2; ks++)
          sc[qt][nt] = mfma16(kb[nt][ks], aq[qt][ks], sc[qt][nt]);
      }
    __builtin_amdgcn_s_setprio(0);

    // ---- bias + exp2 + row-sum + pack into p_lds ----
    #pragma unroll
    for (int qt = 0; qt < 2; qt++) {
      const int qbase = t0 + qt * 64 + w * 16;
      bool alllo = (s0 <= qbase - 79);
      bool allhi = (s0 >= qbase + 31);
      if (alllo || allhi) {
        float bb = alllo ? biasLo[qt] : biasHi[qt];
        #pragma unroll
        for (int nt = 0; nt < 4; nt++)
          #pragma unroll
          for (int reg = 0; reg < 4; reg++) sc[qt][nt][reg] += bb;
      } else {
        int ql = qt * 64 + w * 16 + l16;
        #pragma unroll
        for (int nt = 0; nt < 4; nt++)
          #pragma unroll
          for (int reg = 0; reg < 4; reg++) {
            int delta = (s0 + 16 * nt + 4 * quad + reg) - (qbase + l16);
            delta = min(max(delta, -16), 16) + 16;
            sc[qt][nt][reg] += rel_lds[ql * 33 + delta];
          }
      }
      #pragma unroll
      for (int nt = 0; nt < 4; nt++) {
        #pragma unroll
        for (int reg = 0; reg < 4; reg++) {
          float p = exp2_hw(sc[qt][nt][reg]);
          sc[qt][nt][reg] = p;
          rsum[qt] += p;
        }
        unsigned w0 = pk_bf16(sc[qt][nt][0], sc[qt][nt][1]);
        unsigned w1 = pk_bf16(sc[qt][nt][2], sc[qt][nt][3]);
        int srot = (16 * nt + 4 * quad + 4 * l16) & 63;   // rotation swizzle
        *(uint2*)(p_lds[w] + (qt * 16 + l16) * 64 + srot) = make_uint2(w0, w1);
      }
    }

    // ---- P A-fragments ----
    short8 ap[2][2];
    #pragma unroll
    for (int qt = 0; qt < 2; qt++)
      #pragma unroll
      for (int ks = 0; ks < 2; ks++) {
        int s1 = (32 * ks + 8 * quad + 4 * l16) & 63;
        int s2 = (s1 + 4) & 63;
        union { short8 v; uint2 u[2]; } pu;
        pu.u[0] = *(const uint2*)(p_lds[w] + (qt * 16 + l16) * 64 + s1);
        pu.u[1] = *(const uint2*)(p_lds[w] + (qt * 16 + l16) * 64 + s2);
        ap[qt][ks] = pu.v;
      }

    // ---- V fragments once, O += P V for both q-groups ----
    __builtin_amdgcn_s_setprio(1);
    #pragma unroll
    for (int dt = 0; dt < 4; dt++) {
      short8 vb[2];
      #pragma unroll
      for (int ks = 0; ks < 2; ks++) {
        int drow = dt * 16 + l16;
        vb[ks] = *(const short8*)(Vtile[cur] + drow * 64
                                  + (((quad + 4 * ks) ^ (l16 & 7)) << 3));
      }
      #pragma unroll
      for (int qt = 0; qt < 2; qt++)
        #pragma unroll
        for (int ks = 0; ks < 2; ks++)
          o[qt][dt] = mfma16(ap[qt][ks], vb[ks], o[qt][dt]);
    }
    __builtin_amdgcn_s_setprio(0);
  }
  #undef STAGE_KV

  // ---- row-sum reduce + normalize + store (pk-packed conversion) ----
  #pragma unroll
  for (int qt = 0; qt < 2; qt++) {
    float rs = rsum[qt];
    rs += __shfl_xor(rs, 16, 64);
    rs += __shfl_xor(rs, 32, 64);
    float inv[4];
    #pragma unroll
    for (int reg = 0; reg < 4; reg++)
      inv[reg] = 1.0f / __shfl(rs, quad * 4 + reg, 64);
    #pragma unroll
    for (int dt = 0; dt < 4; dt++) {
      unsigned u01 = pk_bf16(o[qt][dt][0] * inv[0], o[qt][dt][1] * inv[1]);
      unsigned u23 = pk_bf16(o[qt][dt][2] * inv[2], o[qt][dt][3] * inv[3]);
      int tg = t0 + qt * 64 + w * 16 + quad * 4;
      size_t base = ((size_t)tg * 4 + b) * 1024 + h * 64 + dt * 16 + l16;
      attn_ws[base]         = (short)u01;
      attn_ws[base + 4096]  = (short)(u01 >> 16);
      attn_ws[base + 8192]  = (short)u23;
      attn_ws[base + 12288] = (short)(u23 >> 16);
    }
  }
}

// ---------------------------------------------------------------------------
// Kernel 3: out = attn @ out_w^T + out_b, fp32 (T,B,E).
// 64x128 tiles, grid (64, 8), rotation-swizzled LDS.
// ---------------------------------------------------------------------------
__global__ void __launch_bounds__(256) gemm_outproj(
    const short* __restrict__ A, const short* __restrict__ W,
    const float* __restrict__ bias, float* __restrict__ out)
{
  __shared__ __align__(16) short Atile[2 * 64 * 32];    // 8 KB
  __shared__ __align__(16) short Btile[2 * 128 * 32];   // 16 KB
  const int tid = threadIdx.x;
  const int m0 = blockIdx.x * 64, n0 = blockIdx.y * 128;
  const int lane = tid & 63, w = tid >> 6;
  const int quad = lane >> 4, l16 = lane & 15;
  const int wm = (w >> 1) * 32, wn = (w & 1) * 64;

  floatx4 acc[2][4];
  #pragma unroll
  for (int mt = 0; mt < 2; mt++)
    #pragma unroll
    for (int nt = 0; nt < 4; nt++) acc[mt][nt] = (floatx4)(0.0f);

  #define STAGE_OP(KK, BUF)                                                  \
    {                                                                        \
      _Pragma("unroll")                                                      \
      for (int i = 0; i < 2; i++) {                                          \
        int seg = i * 256 + tid;         /* 512 segs: B tile 128x32 */       \
        int row = seg >> 2, p = seg & 3;                                     \
        int ck = (p - ((row >> 1) & 3)) & 3;                                 \
        async_copy16(W + (size_t)(n0 + row) * 1024 + (KK) + ck * 8,          \
                     Btile + (size_t)((BUF) * 4096 + (i * 256 + w * 64) * 8)); \
      }                                                                      \
      {                                                                      \
        int row = tid >> 2, p = tid & 3; /* 256 segs: A tile 64x32 */        \
        int ck = (p - ((row >> 1) & 3)) & 3;                                 \
        async_copy16(A + (size_t)(m0 + row) * 1024 + (KK) + ck * 8,          \
                     Atile + (size_t)((BUF) * 2048 + (w * 64) * 8));         \
      }                                                                      \
    }

  STAGE_OP(0, 0);
  for (int kk = 0; kk < 1024; kk += 32) {
    const int cur = (kk >> 5) & 1;
    const short* Ac = Atile + cur * 2048;
    const short* Bc = Btile + cur * 4096;
    __syncthreads();
    if (kk + 32 < 1024) STAGE_OP(kk + 32, 1 - cur);
    short8 af[2], bfr[4];
    #pragma unroll
    for (int mt = 0; mt < 2; mt++) {
      int R = wm + mt * 16 + l16;
      af[mt] = *(const short8*)(Ac + R * 32 + ((quad + (R >> 1)) & 3) * 8);
    }
    #pragma unroll
    for (int nt = 0; nt < 4; nt++) {
      int R = wn + nt * 16 + l16;
      bfr[nt] = *(const short8*)(Bc + R * 32 + ((quad + (R >> 1)) & 3) * 8);
    }
    #pragma unroll
    for (int mt = 0; mt < 2; mt++)
      #pragma unroll
      for (int nt = 0; nt < 4; nt++)
        acc[mt][nt] = mfma16(af[mt], bfr[nt], acc[mt][nt]);
  }
  #undef STAGE_OP

  #pragma unroll
  for (int nt = 0; nt < 4; nt++) {
    int f = n0 + wn + nt * 16 + l16;
    float bv = bias[f];
    #pragma unroll
    for (int mt = 0; mt < 2; mt++) {
      #pragma unroll
      for (int reg = 0; reg < 4; reg++) {
        int r = m0 + wm + mt * 16 + quad * 4 + reg;
        out[(size_t)r * 1024 + f] = acc[mt][nt][reg] + bv;
      }
    }
  }
}

extern "C" void kernel_launch(void* const* d_in, const int* in_sizes, int n_in,
                              void* d_out, int out_size, void* d_ws, size_t ws_size,
                              hipStream_t stream) {
  const float* query = (const float*)d_in[0];   // (T,B,E) fp32
  const float* in_w  = (const float*)d_in[1];   // (3E,E)  fp32
  const float* in_b  = (const float*)d_in[2];   // (3E,)   fp32
  const float* relk  = (const float*)d_in[3];   // (33,E)  fp32
  const float* out_w = (const float*)d_in[4];   // (E,E)   fp32
  const float* out_b = (const float*)d_in[5];   // (E,)    fp32
  float* out = (float*)d_out;                   // (T,B,E) fp32

  short* qry_bf = (short*)d_ws;                         // (B,T,E) bf16  8MB
  short* win_bf = qry_bf + (size_t)4096 * 1024;         // 3072x1024 bf16  6MB
  short* wout_bf = win_bf + (size_t)3072 * 1024;        // 1024x1024 bf16  2MB
  short* q_ws   = wout_bf + (size_t)1024 * 1024;        // (64,1024,64) bf16  8MB
  short* k_ws   = q_ws + (size_t)64 * 1024 * 64;        // (64,1024,64) bf16  8MB
  short* v_ws   = k_ws + (size_t)64 * 1024 * 64;        // (64,64,1024) bf16  8MB
  short* att_ws = v_ws + (size_t)64 * 1024 * 64;        // (4096,1024)  bf16  8MB

  convert_all_kernel<<<4096, 256, 0, stream>>>(query, in_w, out_w,
                                               qry_bf, win_bf, wout_bf);
  gemm_qkv<<<192, 512, 0, stream>>>(qry_bf, win_bf, in_b, q_ws, k_ws, v_ws);
  attn_kernel<<<512, 256, 0, stream>>>(q_ws, k_ws, v_ws, relk, att_ws);
  gemm_outproj<<<dim3(64, 8), 256, 0, stream>>>(att_ws, wout_bf, out_b, out);
}

// Round 4
// 168.304 us; speedup vs baseline: 1.0534x; 1.0534x over previous
//
#include <hip/hip_runtime.h>
#include <hip/hip_bf16.h>

typedef __attribute__((ext_vector_type(8))) short short8;
typedef __attribute__((ext_vector_type(4))) float floatx4;

// Problem constants: T=1024, B=4, E=1024, H=16, D=64, L=16
// Inputs/outputs fp32; internals bf16 MFMA with fp32 accumulation.
// Softmax runs in the exp2 domain: q is pre-scaled by 0.125*log2(e), so
// scores (qk + rel-bias) are already in log2 units and p = exp2(s).

#define QSCALE 0.18033688011112043f   // 0.125 * log2(e)

__device__ __forceinline__ short f2bf(float x) {
  union { float f; unsigned u; } cv; cv.f = x;
  unsigned u = cv.u + (0x7FFFu + ((cv.u >> 16) & 1u));  // RNE
  return (short)(u >> 16);
}

// gfx950 v_cvt_pk_bf16_f32 via hip_bf16 API: 1 VALU op per 2 values.
__device__ __forceinline__ unsigned pk_bf16(float a, float b) {
  union { __hip_bfloat162 h; unsigned u; } cv;
  cv.h = __float22bfloat162_rn(make_float2(a, b));
  return cv.u;
}

// v_exp_f32 computes 2^x directly.
__device__ __forceinline__ float exp2_hw(float x) {
  return __builtin_amdgcn_exp2f(x);
}

__device__ __forceinline__ floatx4 mfma16(short8 a, short8 b, floatx4 c) {
  return __builtin_amdgcn_mfma_f32_16x16x32_bf16(a, b, c, 0, 0, 0);
}

__device__ __forceinline__ void async_copy16(const void* g, void* l) {
  __builtin_amdgcn_global_load_lds((const __attribute__((address_space(1))) void*)g,
                                   (__attribute__((address_space(3))) void*)l, 16, 0, 0);
}

// ---------------------------------------------------------------------------
// Kernel 0: fp32 -> bf16 for query / in_proj_weight / out_w in ONE launch.
// query is ALSO transposed (T,B,E) -> (B,T,E).
// ---------------------------------------------------------------------------
__global__ void __launch_bounds__(256) convert_all_kernel(
    const float* __restrict__ s0, const float* __restrict__ s1,
    const float* __restrict__ s2,
    short* __restrict__ d0, short* __restrict__ d1, short* __restrict__ d2)
{
  int i = blockIdx.x * 256 + threadIdx.x;
  if (i < 524288) {               // query with transpose
    int e8 = i & 127, b = (i >> 7) & 3, t = i >> 9;
    const float4* s = (const float4*)s0 + (size_t)i * 2;
    float4 a = s[0], c = s[1];
    uint4 o = make_uint4(pk_bf16(a.x, a.y), pk_bf16(a.z, a.w),
                         pk_bf16(c.x, c.y), pk_bf16(c.z, c.w));
    *(uint4*)(d0 + (size_t)b * 1048576 + t * 1024 + e8 * 8) = o;
  } else {                        // weights, straight copy
    const float* src; short* dst; int off;
    if (i < 917504) { src = s1; dst = d1; off = i - 524288; }
    else            { src = s2; dst = d2; off = i - 917504; }
    const float4* s = (const float4*)src + (size_t)off * 2;
    float4 a = s[0], c = s[1];
    uint4 o = make_uint4(pk_bf16(a.x, a.y), pk_bf16(a.z, a.w),
                         pk_bf16(c.x, c.y), pk_bf16(c.z, c.w));
    *(uint4*)(dst + (size_t)off * 8) = o;
  }
}

// ---------------------------------------------------------------------------
// Kernel 1: qkv = query_bt @ in_proj_weight^T + bias.
// 256x192 tile, BK=64, 8 waves (2Mx4N; per-wave 128x48), grid (16,16) = 256
// blocks = exactly 1 per CU (full machine, LDS 112 KB).
// Simple proven 2-phase pipeline (attn/outproj structure): per K-tile
//   {22x ds_read_b128 (cur) | 7x global_load_lds (nxt) | 48 MFMA |
//    vmcnt(0) | s_barrier}
// One drain point per tile; the DMA's L2 latency (~900 cyc) is covered by
// the ~2000-cyc MFMA phase. xor-8 swizzled LDS (conflict-free b128 reads).
// 'which' (q/k/v) is resolved per-nt (16-wide, uniform) since the 1024
// boundary falls inside a 192-wide tile.
// ---------------------------------------------------------------------------
__global__ void __launch_bounds__(512, 2) gemm_qkv(
    const short* __restrict__ A, const short* __restrict__ W,
    const float* __restrict__ bias,
    short* __restrict__ q_ws, short* __restrict__ k_ws, short* __restrict__ v_ws)
{
  __shared__ __align__(16) short Atile[2 * 256 * 64];   // 64 KB
  __shared__ __align__(16) short Btile[2 * 192 * 64];   // 48 KB
  const int tid = threadIdx.x, lane = tid & 63, w = tid >> 6;
  const int quad = lane >> 4, l16 = lane & 15;
  const int m0 = blockIdx.x * 256, n0 = blockIdx.y * 192;
  const int wmh = (w >> 2);             // 0/1: which 128-row half of A tile
  const int wn = (w & 3) * 48;          // wave's 48-col window in B tile

  const short* Ag = A + (size_t)m0 * 1024;
  const short* Wg = W + (size_t)n0 * 1024;

  floatx4 acc[8][3];
  #pragma unroll
  for (int mt = 0; mt < 8; mt++)
    #pragma unroll
    for (int nt = 0; nt < 3; nt++) acc[mt][nt] = (floatx4)(0.0f);

  // A: 256x64 bf16 = 2048 16B-segs -> 4 loads/thread.
  // B: 192x64 bf16 = 1536 16B-segs -> 3 loads/thread.
  // seg s: row = s>>3, slot p = s&7 holds global chunk ck = p^(row&7).
  #define STAGE_A(kc, buf)                                                   \
    {                                                                        \
      _Pragma("unroll")                                                      \
      for (int i = 0; i < 4; i++) {                                          \
        int seg = i * 512 + tid;                                             \
        int row = seg >> 3, p = seg & 7;                                     \
        int ck = p ^ (row & 7);                                              \
        async_copy16(Ag + (size_t)row * 1024 + (kc) * 64 + ck * 8,           \
                     Atile + (buf) * 16384 + (size_t)(i * 512 + w * 64) * 8);\
      }                                                                      \
    }
  #define STAGE_B(kc, buf)                                                   \
    {                                                                        \
      _Pragma("unroll")                                                      \
      for (int i = 0; i < 3; i++) {                                          \
        int seg = i * 512 + tid;                                             \
        int row = seg >> 3, p = seg & 7;                                     \
        int ck = p ^ (row & 7);                                              \
        async_copy16(Wg + (size_t)row * 1024 + (kc) * 64 + ck * 8,           \
                     Btile + (buf) * 12288 + (size_t)(i * 512 + w * 64) * 8);\
      }                                                                      \
    }

  STAGE_A(0, 0); STAGE_B(0, 0);
  asm volatile("s_waitcnt vmcnt(0)" ::: "memory");
  __builtin_amdgcn_s_barrier();

  for (int kt = 0; kt < 16; ++kt) {
    const int cur = kt & 1, nxt = cur ^ 1;
    const int kc1 = (kt + 1 < 16) ? kt + 1 : 15;   // ghost re-stage on tail

    // ---- all fragment reads for this tile (22 x ds_read_b128) ----
    short8 af[8][2], bf[3][2];
    #pragma unroll
    for (int mt = 0; mt < 8; mt++) {
      int r = mt * 16 + l16;                        // 0..127 in wave's half
      int gr = wmh * 128 + r;                       // global A-tile row
      #pragma unroll
      for (int ks = 0; ks < 2; ks++)
        af[mt][ks] = *(const short8*)(Atile + cur * 16384 + gr * 64
                                      + (((quad + 4 * ks) ^ (r & 7)) << 3));
    }
    #pragma unroll
    for (int nt = 0; nt < 3; nt++) {
      int row = wn + nt * 16 + l16;                 // 0..191 (wn mult of 48)
      #pragma unroll
      for (int ks = 0; ks < 2; ks++)
        bf[nt][ks] = *(const short8*)(Btile + cur * 12288 + row * 64
                                      + (((quad + 4 * ks) ^ (row & 7)) << 3));
    }

    // ---- prefetch next tile while MFMA runs ----
    STAGE_A(kc1, nxt); STAGE_B(kc1, nxt);

    // ---- 48 MFMA ----
    __builtin_amdgcn_s_setprio(1);
    #pragma unroll
    for (int mt = 0; mt < 8; mt++)
      #pragma unroll
      for (int nt = 0; nt < 3; nt++)
        #pragma unroll
        for (int ks = 0; ks < 2; ks++)
          acc[mt][nt] = mfma16(af[mt][ks], bf[nt][ks], acc[mt][nt]);
    __builtin_amdgcn_s_setprio(0);
    __builtin_amdgcn_sched_barrier(0);

    asm volatile("s_waitcnt vmcnt(0)" ::: "memory");   // nxt landed
    __builtin_amdgcn_s_barrier();
  }
  #undef STAGE_A
  #undef STAGE_B

  // ---- epilogue: which (q/k/v) resolved per nt (16-wide, uniform) ----
  #pragma unroll
  for (int nt = 0; nt < 3; nt++) {
    int f = n0 + wn + nt * 16 + l16;          // 0..3071
    float bv = bias[f];
    int which = f >> 10;                      // 0=q 1=k 2=v
    int h = (f >> 6) & 15;
    int d = f & 63;
    if (which == 2) {
      #pragma unroll
      for (int mt = 0; mt < 8; mt++) {
        int r0 = m0 + wmh * 128 + mt * 16 + quad * 4;   // row = b*1024 + t
        int t = r0 & 1023, bb = r0 >> 10;
        int bh = bb * 16 + h;
        unsigned lo = pk_bf16(acc[mt][nt][0] + bv, acc[mt][nt][1] + bv);
        unsigned hi = pk_bf16(acc[mt][nt][2] + bv, acc[mt][nt][3] + bv);
        *(uint2*)(v_ws + ((size_t)bh * 64 + d) * 1024 + t) = make_uint2(lo, hi);
      }
    } else {
      short* dst = which ? k_ws : q_ws;
      const float sc = which ? 1.0f : QSCALE;
      #pragma unroll
      for (int mt = 0; mt < 8; mt++) {
        int r0 = m0 + wmh * 128 + mt * 16 + quad * 4;
        int t = r0 & 1023, bb = r0 >> 10;
        int bh = bb * 16 + h;
        unsigned u01 = pk_bf16((acc[mt][nt][0] + bv) * sc, (acc[mt][nt][1] + bv) * sc);
        unsigned u23 = pk_bf16((acc[mt][nt][2] + bv) * sc, (acc[mt][nt][3] + bv) * sc);
        size_t base = ((size_t)bh * 1024 + t) * 64 + d;
        dst[base]           = (short)u01;
        dst[base + 64]      = (short)(u01 >> 16);
        dst[base + 128]     = (short)u23;
        dst[base + 192]     = (short)(u23 >> 16);
      }
    }
  }
}

// ---------------------------------------------------------------------------
// Kernel 2: flash-style attention, S^T formulation, 2 q-groups per wave.
//  - K/V double-buffered: ONE barrier per s-tile, DMA(t+1) flies under
//    compute(t). LDS 66 KB is free: occupancy is grid-capped at 2 blocks/CU.
//  - XCD head-affinity swizzle keeps per-head K/V L2-resident.
//  - exp2-domain softmax: p = 2^s via v_exp_f32, q pre-scaled by QSCALE.
//  - T5 setprio around QK and PV MFMA clusters.
// block = (bh, 128 q-rows); 4 waves. grid 512, block 256.
// ---------------------------------------------------------------------------
__global__ void __launch_bounds__(256) attn_kernel(
    const short* __restrict__ q_ws, const short* __restrict__ k_ws,
    const short* __restrict__ v_ws, const float* __restrict__ relk,
    short* __restrict__ attn_ws)
{
  __shared__ float rel_lds[128 * 33];                   // 16896 B
  __shared__ __align__(16) short Ktile[2][64 * 64];     // 16384 B
  __shared__ __align__(16) short Vtile[2][64 * 64];     // 16384 B
  __shared__ __align__(16) short p_lds[4][32 * 64];     // 16384 B
  const int tid = threadIdx.x, lane = tid & 63, w = tid >> 6;
  const int quad = lane >> 4, l16 = lane & 15;
  // XCD swizzle: head = 8*(blk&7) + (blk>>3)&7, chunk = blk>>6
  const int bh = 8 * ((int)blockIdx.x & 7) + (((int)blockIdx.x >> 3) & 7);
  const int t0 = ((int)blockIdx.x >> 6) * 128;
  const int b = bh >> 4, h = bh & 15;

  // Q fragments: q-row(qt) = t0 + qt*64 + w*16 + l16
  short8 aq[2][2];
  #pragma unroll
  for (int qt = 0; qt < 2; qt++)
    #pragma unroll
    for (int ks = 0; ks < 2; ks++)
      aq[qt][ks] = *(const short8*)(q_ws
          + ((size_t)bh * 1024 + t0 + qt * 64 + w * 16 + l16) * 64
          + ks * 32 + quad * 8);

  // ---- stage relk[0:33][0:64] as bf16 into Ktile[0] (xor-swizzled, pad 48)
  for (int i = tid; i < 48 * 8; i += 256) {
    int row = i >> 3, p = i & 7;
    short8 val;
    if (row < 33) {
      const float* src = relk + row * 1024 + p * 8;
      float4 a = *(const float4*)src, c = *(const float4*)(src + 4);
      val[0] = f2bf(a.x); val[1] = f2bf(a.y); val[2] = f2bf(a.z); val[3] = f2bf(a.w);
      val[4] = f2bf(c.x); val[5] = f2bf(c.y); val[6] = f2bf(c.z); val[7] = f2bf(c.w);
    } else {
      val = (short8)0;
    }
    *(short8*)(Ktile[0] + row * 64 + ((p ^ (row & 7)) << 3)) = val;
  }
  __syncthreads();

  // ---- rel_lds[tl][j] = q[tl] . relk[j]   (log2-domain, q pre-scaled)
  #pragma unroll
  for (int qt = 0; qt < 2; qt++) {
    #pragma unroll
    for (int jt = 0; jt < 3; jt++) {
      floatx4 scR = (floatx4)(0.0f);
      #pragma unroll
      for (int ks = 0; ks < 2; ks++) {
        int rrow = jt * 16 + l16;
        int ck = (quad + 4 * ks) ^ (rrow & 7);
        short8 rb = *(const short8*)(Ktile[0] + rrow * 64 + ck * 8);
        scR = mfma16(aq[qt][ks], rb, scR);
      }
      int j = jt * 16 + l16;
      if (j < 33) {
        #pragma unroll
        for (int reg = 0; reg < 4; reg++) {
          int tl = qt * 64 + w * 16 + quad * 4 + reg;
          rel_lds[tl * 33 + j] = scR[reg];
        }
      }
    }
  }
  __syncthreads();   // rel_lds ready; Ktile free for K/V staging

  float biasLo[2], biasHi[2];
  #pragma unroll
  for (int qt = 0; qt < 2; qt++) {
    int ql = qt * 64 + w * 16 + l16;
    biasLo[qt] = rel_lds[ql * 33 + 0];
    biasHi[qt] = rel_lds[ql * 33 + 32];
  }

  floatx4 o[2][4];
  #pragma unroll
  for (int qt = 0; qt < 2; qt++)
    #pragma unroll
    for (int dt = 0; dt < 4; dt++) o[qt][dt] = (floatx4)(0.0f);
  float rsum[2] = {0.f, 0.f};

  const short* kg = k_ws + (size_t)bh * 1024 * 64;
  const short* vg = v_ws + (size_t)bh * 64 * 1024;

  #define STAGE_KV(S0, BUF)                                                  \
    {                                                                        \
      _Pragma("unroll")                                                      \
      for (int i = 0; i < 2; i++) {                                          \
        int seg = i * 256 + tid;                                             \
        int row = seg >> 3, p = seg & 7;                                     \
        int ck = p ^ (row & 7);                                              \
        async_copy16(kg + (size_t)((S0) + row) * 64 + ck * 8,                \
                     Ktile[BUF] + (size_t)(i * 256 + w * 64) * 8);           \
        async_copy16(vg + (size_t)row * 1024 + (S0) + ck * 8,                \
                     Vtile[BUF] + (size_t)(i * 256 + w * 64) * 8);           \
      }                                                                      \
    }

  STAGE_KV(0, 0);

  for (int st = 0; st < 16; st++) {
    const int s0 = st * 64;
    const int cur = st & 1;
    __syncthreads();                // drains DMA(st); WAR for DMA(st+1)
    if (st < 15) STAGE_KV(s0 + 64, 1 - cur);

    // ---- K fragments once into registers, reused by both q-groups ----
    short8 kb[4][2];
    #pragma unroll
    for (int nt = 0; nt < 4; nt++)
      #pragma unroll
      for (int ks = 0; ks < 2; ks++) {
        int srow = nt * 16 + l16;
        kb[nt][ks] = *(const short8*)(Ktile[cur] + srow * 64
                                      + (((quad + 4 * ks) ^ (l16 & 7)) << 3));
      }

    // ---- S^T = K Q^T for both q-groups ----
    floatx4 sc[2][4];
    __builtin_amdgcn_s_setprio(1);
    #pragma unroll
    for (int qt = 0; qt < 2; qt++)
      #pragma unroll
      for (int nt = 0; nt < 4; nt++) {
        sc[qt][nt] = (floatx4)(0.0f);
        #pragma unroll
        for (int ks = 0; ks < 2; ks++)
          sc[qt][nt] = mfma16(kb[nt][ks], aq[qt][ks], sc[qt][nt]);
      }
    __builtin_amdgcn_s_setprio(0);

    // ---- bias + exp2 + row-sum + pack into p_lds ----
    #pragma unroll
    for (int qt = 0; qt < 2; qt++) {
      const int qbase = t0 + qt * 64 + w * 16;
      bool alllo = (s0 <= qbase - 79);
      bool allhi = (s0 >= qbase + 31);
      if (alllo || allhi) {
        float bb = alllo ? biasLo[qt] : biasHi[qt];
        #pragma unroll
        for (int nt = 0; nt < 4; nt++)
          #pragma unroll
          for (int reg = 0; reg < 4; reg++) sc[qt][nt][reg] += bb;
      } else {
        int ql = qt * 64 + w * 16 + l16;
        #pragma unroll
        for (int nt = 0; nt < 4; nt++)
          #pragma unroll
          for (int reg = 0; reg < 4; reg++) {
            int delta = (s0 + 16 * nt + 4 * quad + reg) - (qbase + l16);
            delta = min(max(delta, -16), 16) + 16;
            sc[qt][nt][reg] += rel_lds[ql * 33 + delta];
          }
      }
      #pragma unroll
      for (int nt = 0; nt < 4; nt++) {
        #pragma unroll
        for (int reg = 0; reg < 4; reg++) {
          float p = exp2_hw(sc[qt][nt][reg]);
          sc[qt][nt][reg] = p;
          rsum[qt] += p;
        }
        unsigned w0 = pk_bf16(sc[qt][nt][0], sc[qt][nt][1]);
        unsigned w1 = pk_bf16(sc[qt][nt][2], sc[qt][nt][3]);
        int srot = (16 * nt + 4 * quad + 4 * l16) & 63;   // rotation swizzle
        *(uint2*)(p_lds[w] + (qt * 16 + l16) * 64 + srot) = make_uint2(w0, w1);
      }
    }

    // ---- P A-fragments ----
    short8 ap[2][2];
    #pragma unroll
    for (int qt = 0; qt < 2; qt++)
      #pragma unroll
      for (int ks = 0; ks < 2; ks++) {
        int s1 = (32 * ks + 8 * quad + 4 * l16) & 63;
        int s2 = (s1 + 4) & 63;
        union { short8 v; uint2 u[2]; } pu;
        pu.u[0] = *(const uint2*)(p_lds[w] + (qt * 16 + l16) * 64 + s1);
        pu.u[1] = *(const uint2*)(p_lds[w] + (qt * 16 + l16) * 64 + s2);
        ap[qt][ks] = pu.v;
      }

    // ---- V fragments once, O += P V for both q-groups ----
    __builtin_amdgcn_s_setprio(1);
    #pragma unroll
    for (int dt = 0; dt < 4; dt++) {
      short8 vb[2];
      #pragma unroll
      for (int ks = 0; ks < 2; ks++) {
        int drow = dt * 16 + l16;
        vb[ks] = *(const short8*)(Vtile[cur] + drow * 64
                                  + (((quad + 4 * ks) ^ (l16 & 7)) << 3));
      }
      #pragma unroll
      for (int qt = 0; qt < 2; qt++)
        #pragma unroll
        for (int ks = 0; ks < 2; ks++)
          o[qt][dt] = mfma16(ap[qt][ks], vb[ks], o[qt][dt]);
    }
    __builtin_amdgcn_s_setprio(0);
  }
  #undef STAGE_KV

  // ---- row-sum reduce + normalize + store (pk-packed conversion) ----
  #pragma unroll
  for (int qt = 0; qt < 2; qt++) {
    float rs = rsum[qt];
    rs += __shfl_xor(rs, 16, 64);
    rs += __shfl_xor(rs, 32, 64);
    float inv[4];
    #pragma unroll
    for (int reg = 0; reg < 4; reg++)
      inv[reg] = 1.0f / __shfl(rs, quad * 4 + reg, 64);
    #pragma unroll
    for (int dt = 0; dt < 4; dt++) {
      unsigned u01 = pk_bf16(o[qt][dt][0] * inv[0], o[qt][dt][1] * inv[1]);
      unsigned u23 = pk_bf16(o[qt][dt][2] * inv[2], o[qt][dt][3] * inv[3]);
      int tg = t0 + qt * 64 + w * 16 + quad * 4;
      size_t base = ((size_t)tg * 4 + b) * 1024 + h * 64 + dt * 16 + l16;
      attn_ws[base]         = (short)u01;
      attn_ws[base + 4096]  = (short)(u01 >> 16);
      attn_ws[base + 8192]  = (short)u23;
      attn_ws[base + 12288] = (short)(u23 >> 16);
    }
  }
}

// ---------------------------------------------------------------------------
// Kernel 3: out = attn @ out_w^T + out_b, fp32 (T,B,E).
// 64x128 tiles, grid (64, 8), rotation-swizzled LDS.
// ---------------------------------------------------------------------------
__global__ void __launch_bounds__(256) gemm_outproj(
    const short* __restrict__ A, const short* __restrict__ W,
    const float* __restrict__ bias, float* __restrict__ out)
{
  __shared__ __align__(16) short Atile[2 * 64 * 32];    // 8 KB
  __shared__ __align__(16) short Btile[2 * 128 * 32];   // 16 KB
  const int tid = threadIdx.x;
  const int m0 = blockIdx.x * 64, n0 = blockIdx.y * 128;
  const int lane = tid & 63, w = tid >> 6;
  const int quad = lane >> 4, l16 = lane & 15;
  const int wm = (w >> 1) * 32, wn = (w & 1) * 64;

  floatx4 acc[2][4];
  #pragma unroll
  for (int mt = 0; mt < 2; mt++)
    #pragma unroll
    for (int nt = 0; nt < 4; nt++) acc[mt][nt] = (floatx4)(0.0f);

  #define STAGE_OP(KK, BUF)                                                  \
    {                                                                        \
      _Pragma("unroll")                                                      \
      for (int i = 0; i < 2; i++) {                                          \
        int seg = i * 256 + tid;         /* 512 segs: B tile 128x32 */       \
        int row = seg >> 2, p = seg & 3;                                     \
        int ck = (p - ((row >> 1) & 3)) & 3;                                 \
        async_copy16(W + (size_t)(n0 + row) * 1024 + (KK) + ck * 8,          \
                     Btile + (size_t)((BUF) * 4096 + (i * 256 + w * 64) * 8)); \
      }                                                                      \
      {                                                                      \
        int row = tid >> 2, p = tid & 3; /* 256 segs: A tile 64x32 */        \
        int ck = (p - ((row >> 1) & 3)) & 3;                                 \
        async_copy16(A + (size_t)(m0 + row) * 1024 + (KK) + ck * 8,          \
                     Atile + (size_t)((BUF) * 2048 + (w * 64) * 8));         \
      }                                                                      \
    }

  STAGE_OP(0, 0);
  for (int kk = 0; kk < 1024; kk += 32) {
    const int cur = (kk >> 5) & 1;
    const short* Ac = Atile + cur * 2048;
    const short* Bc = Btile + cur * 4096;
    __syncthreads();
    if (kk + 32 < 1024) STAGE_OP(kk + 32, 1 - cur);
    short8 af[2], bfr[4];
    #pragma unroll
    for (int mt = 0; mt < 2; mt++) {
      int R = wm + mt * 16 + l16;
      af[mt] = *(const short8*)(Ac + R * 32 + ((quad + (R >> 1)) & 3) * 8);
    }
    #pragma unroll
    for (int nt = 0; nt < 4; nt++) {
      int R = wn + nt * 16 + l16;
      bfr[nt] = *(const short8*)(Bc + R * 32 + ((quad + (R >> 1)) & 3) * 8);
    }
    #pragma unroll
    for (int mt = 0; mt < 2; mt++)
      #pragma unroll
      for (int nt = 0; nt < 4; nt++)
        acc[mt][nt] = mfma16(af[mt], bfr[nt], acc[mt][nt]);
  }
  #undef STAGE_OP

  #pragma unroll
  for (int nt = 0; nt < 4; nt++) {
    int f = n0 + wn + nt * 16 + l16;
    float bv = bias[f];
    #pragma unroll
    for (int mt = 0; mt < 2; mt++) {
      #pragma unroll
      for (int reg = 0; reg < 4; reg++) {
        int r = m0 + wm + mt * 16 + quad * 4 + reg;
        out[(size_t)r * 1024 + f] = acc[mt][nt][reg] + bv;
      }
    }
  }
}

extern "C" void kernel_launch(void* const* d_in, const int* in_sizes, int n_in,
                              void* d_out, int out_size, void* d_ws, size_t ws_size,
                              hipStream_t stream) {
  const float* query = (const float*)d_in[0];   // (T,B,E) fp32
  const float* in_w  = (const float*)d_in[1];   // (3E,E)  fp32
  const float* in_b  = (const float*)d_in[2];   // (3E,)   fp32
  const float* relk  = (const float*)d_in[3];   // (33,E)  fp32
  const float* out_w = (const float*)d_in[4];   // (E,E)   fp32
  const float* out_b = (const float*)d_in[5];   // (E,)    fp32
  float* out = (float*)d_out;                   // (T,B,E) fp32

  short* qry_bf = (short*)d_ws;                         // (B,T,E) bf16  8MB
  short* win_bf = qry_bf + (size_t)4096 * 1024;         // 3072x1024 bf16  6MB
  short* wout_bf = win_bf + (size_t)3072 * 1024;        // 1024x1024 bf16  2MB
  short* q_ws   = wout_bf + (size_t)1024 * 1024;        // (64,1024,64) bf16  8MB
  short* k_ws   = q_ws + (size_t)64 * 1024 * 64;        // (64,1024,64) bf16  8MB
  short* v_ws   = k_ws + (size_t)64 * 1024 * 64;        // (64,64,1024) bf16  8MB
  short* att_ws = v_ws + (size_t)64 * 1024 * 64;        // (4096,1024)  bf16  8MB

  convert_all_kernel<<<4096, 256, 0, stream>>>(query, in_w, out_w,
                                               qry_bf, win_bf, wout_bf);
  gemm_qkv<<<dim3(16, 16), 512, 0, stream>>>(qry_bf, win_bf, in_b, q_ws, k_ws, v_ws);
  attn_kernel<<<512, 256, 0, stream>>>(q_ws, k_ws, v_ws, relk, att_ws);
  gemm_outproj<<<dim3(64, 8), 256, 0, stream>>>(att_ws, wout_bf, out_b, out);
}